// Round 1
// baseline (1925.985 us; speedup 1.0000x reference)
//
#include <hip/hip_runtime.h>

#define NVOX 120000
#define KVOL 27
#define CH 64
#define TOTAL (NVOX * CH)
#define EPSV 1e-5f

// ws layout (floats): [0:64) sum, [64:128) sumsq, [128:192) scale,
// [192:256) bias, [256:320) zero feature row for invalid neighbors.

__launch_bounds__(256)
__global__ void conv_kernel(const float* __restrict__ feats,
                            const float* __restrict__ weight,
                            const int* __restrict__ nbr,
                            const float* __restrict__ zero_row,
                            float* __restrict__ out) {
    const int lane = threadIdx.x & 63;
    const int wave = threadIdx.x >> 6;
    const int v0 = blockIdx.x * 16 + wave * 4;   // 4 voxels per wave, 16 per block

    float a0 = 0.f, a1 = 0.f, a2 = 0.f, a3 = 0.f;

    for (int k = 0; k < KVOL; ++k) {
        const int* nk = nbr + k * NVOX + v0;
        const int i0 = nk[0], i1 = nk[1], i2 = nk[2], i3 = nk[3];
        const float4* r0 = (const float4*)(i0 >= 0 ? feats + (size_t)i0 * CH : zero_row);
        const float4* r1 = (const float4*)(i1 >= 0 ? feats + (size_t)i1 * CH : zero_row);
        const float4* r2 = (const float4*)(i2 >= 0 ? feats + (size_t)i2 * CH : zero_row);
        const float4* r3 = (const float4*)(i3 >= 0 ? feats + (size_t)i3 * CH : zero_row);
        const float* wk = weight + k * CH * CH + lane;   // W[k][c][lane]

#pragma unroll
        for (int c4 = 0; c4 < 16; ++c4) {
            const float4 f0 = r0[c4];
            const float4 f1 = r1[c4];
            const float4 f2 = r2[c4];
            const float4 f3 = r3[c4];
            const float w0 = wk[(c4 * 4 + 0) * CH];
            const float w1 = wk[(c4 * 4 + 1) * CH];
            const float w2 = wk[(c4 * 4 + 2) * CH];
            const float w3 = wk[(c4 * 4 + 3) * CH];
            a0 = fmaf(f0.x, w0, fmaf(f0.y, w1, fmaf(f0.z, w2, fmaf(f0.w, w3, a0))));
            a1 = fmaf(f1.x, w0, fmaf(f1.y, w1, fmaf(f1.z, w2, fmaf(f1.w, w3, a1))));
            a2 = fmaf(f2.x, w0, fmaf(f2.y, w1, fmaf(f2.z, w2, fmaf(f2.w, w3, a2))));
            a3 = fmaf(f3.x, w0, fmaf(f3.y, w1, fmaf(f3.z, w2, fmaf(f3.w, w3, a3))));
        }
    }

    out[(size_t)(v0 + 0) * CH + lane] = a0;
    out[(size_t)(v0 + 1) * CH + lane] = a1;
    out[(size_t)(v0 + 2) * CH + lane] = a2;
    out[(size_t)(v0 + 3) * CH + lane] = a3;
}

__launch_bounds__(256)
__global__ void reduce_stats(const float* __restrict__ out, float* __restrict__ stats) {
    const int tid = threadIdx.x;
    const int ch = tid & 63;
    float s = 0.f, s2 = 0.f;
    // grid stride is a multiple of 64, so each thread stays on one channel.
    for (int e = blockIdx.x * 256 + tid; e < TOTAL; e += gridDim.x * 256) {
        const float x = out[e];
        s += x;
        s2 = fmaf(x, x, s2);
    }
    __shared__ float ls[256];
    __shared__ float ls2[256];
    ls[tid] = s;
    ls2[tid] = s2;
    __syncthreads();
    if (tid < 64) {
        s  = ls[tid] + ls[tid + 64] + ls[tid + 128] + ls[tid + 192];
        s2 = ls2[tid] + ls2[tid + 64] + ls2[tid + 128] + ls2[tid + 192];
        atomicAdd(&stats[ch], s);
        atomicAdd(&stats[64 + ch], s2);
    }
}

__global__ void finalize_stats(float* __restrict__ ws,
                               const float* __restrict__ gamma,
                               const float* __restrict__ beta) {
    const int c = threadIdx.x;   // 64 threads
    const float inv_n = 1.0f / (float)NVOX;
    const float mean = ws[c] * inv_n;
    const float var = ws[64 + c] * inv_n - mean * mean;
    const float scale = gamma[c] * rsqrtf(var + EPSV);
    ws[128 + c] = scale;
    ws[192 + c] = beta[c] - mean * scale;
}

__launch_bounds__(256)
__global__ void bn_relu(float* __restrict__ out, const float* __restrict__ ws) {
    const int e = blockIdx.x * 256 + threadIdx.x;   // float4 index
    float4* o4 = (float4*)out;
    const int cb = (e & 15) * 4;                    // channel base of this float4
    float4 x = o4[e];
    const float s0 = ws[128 + cb + 0], b0 = ws[192 + cb + 0];
    const float s1 = ws[128 + cb + 1], b1 = ws[192 + cb + 1];
    const float s2 = ws[128 + cb + 2], b2 = ws[192 + cb + 2];
    const float s3 = ws[128 + cb + 3], b3 = ws[192 + cb + 3];
    x.x = fmaxf(fmaf(x.x, s0, b0), 0.f);
    x.y = fmaxf(fmaf(x.y, s1, b1), 0.f);
    x.z = fmaxf(fmaf(x.z, s2, b2), 0.f);
    x.w = fmaxf(fmaf(x.w, s3, b3), 0.f);
    o4[e] = x;
}

extern "C" void kernel_launch(void* const* d_in, const int* in_sizes, int n_in,
                              void* d_out, int out_size, void* d_ws, size_t ws_size,
                              hipStream_t stream) {
    const float* feats  = (const float*)d_in[0];   // [N, 64]
    const float* weight = (const float*)d_in[1];   // [27, 64, 64]
    const float* gamma  = (const float*)d_in[2];   // [64]
    const float* beta   = (const float*)d_in[3];   // [64]
    const int*   nbr    = (const int*)d_in[4];     // [27, N]
    float* out = (float*)d_out;                    // [N, 64]
    float* ws  = (float*)d_ws;

    // zero stats + zero-row (ws is re-poisoned 0xAA before every launch)
    hipMemsetAsync(d_ws, 0, 320 * sizeof(float), stream);

    conv_kernel<<<NVOX / 16, 256, 0, stream>>>(feats, weight, nbr, ws + 256, out);
    reduce_stats<<<512, 256, 0, stream>>>(out, ws);
    finalize_stats<<<1, 64, 0, stream>>>(ws, gamma, beta);
    bn_relu<<<TOTAL / 4 / 256, 256, 0, stream>>>(out, ws);
}

// Round 2
// 343.326 us; speedup vs baseline: 5.6098x; 5.6098x over previous
//
#include <hip/hip_runtime.h>

#define NVOX 120000
#define KVOL 27
#define CH 64
#define TOTAL (NVOX * CH)
#define EPSV 1e-5f

typedef __attribute__((ext_vector_type(8))) short bf16x8;
typedef __attribute__((ext_vector_type(4))) float f32x4;

__device__ __forceinline__ unsigned short f2bf(float f) {
    unsigned int u = __builtin_bit_cast(unsigned int, f);
    u += 0x7FFFu + ((u >> 16) & 1u);          // RNE
    return (unsigned short)(u >> 16);
}

// ---- pre-passes -----------------------------------------------------------

// weight[k][c][d] fp32 -> Wt[k][d][c] bf16   (27*64*64 elems)
__global__ void convert_w(const float* __restrict__ w, unsigned short* __restrict__ wt) {
    const int t = blockIdx.x * 256 + threadIdx.x;      // t = k*4096 + d*64 + c
    if (t >= KVOL * CH * CH) return;
    const int c = t & 63;
    const int d = (t >> 6) & 63;
    const int k = t >> 12;
    wt[t] = f2bf(w[k * 4096 + c * 64 + d]);
}

// feats fp32 -> bf16, 4 elems/thread
__global__ void convert_f(const float* __restrict__ f, unsigned short* __restrict__ fb) {
    const int t = blockIdx.x * 256 + threadIdx.x;      // float4 index
    const float4 x = ((const float4*)f)[t];
    ushort4 y;
    y.x = f2bf(x.x); y.y = f2bf(x.y); y.z = f2bf(x.z); y.w = f2bf(x.w);
    ((ushort4*)fb)[t] = y;
}

// ---- conv: gather-GEMM with MFMA ------------------------------------------
// USE_BF: A-rows from pre-converted bf16 feats; else fp32 feats + in-reg cvt.
template <bool USE_BF>
__launch_bounds__(256)
__global__ void conv_mfma(const unsigned short* __restrict__ featsB,
                          const float* __restrict__ feats32,
                          const unsigned short* __restrict__ Wt,
                          const int* __restrict__ nbr,
                          float* __restrict__ out) {
    const int lane = threadIdx.x & 63;
    const int wave = threadIdx.x >> 6;
    const int m = lane & 15;          // voxel-within-tile for A, col for B/D
    const int quad = lane >> 4;       // k-quad
    const int v0 = (blockIdx.x * 4 + wave) * 16;

    f32x4 acc0 = {0.f, 0.f, 0.f, 0.f};
    f32x4 acc1 = {0.f, 0.f, 0.f, 0.f};
    f32x4 acc2 = {0.f, 0.f, 0.f, 0.f};
    f32x4 acc3 = {0.f, 0.f, 0.f, 0.f};

    for (int k = 0; k < KVOL; ++k) {
        const int idx = nbr[k * NVOX + v0 + m];
        const int safe = idx < 0 ? 0 : idx;

        bf16x8 a0, a1;
        if (USE_BF) {
            const unsigned short* row = featsB + (size_t)safe * CH + quad * 8;
            a0 = *(const bf16x8*)(row);
            a1 = *(const bf16x8*)(row + 32);
        } else {
            const float* row = feats32 + (size_t)safe * CH + quad * 8;
            const float4 p0 = *(const float4*)(row);
            const float4 p1 = *(const float4*)(row + 4);
            const float4 p2 = *(const float4*)(row + 32);
            const float4 p3 = *(const float4*)(row + 36);
            a0 = (bf16x8){(short)f2bf(p0.x), (short)f2bf(p0.y), (short)f2bf(p0.z), (short)f2bf(p0.w),
                          (short)f2bf(p1.x), (short)f2bf(p1.y), (short)f2bf(p1.z), (short)f2bf(p1.w)};
            a1 = (bf16x8){(short)f2bf(p2.x), (short)f2bf(p2.y), (short)f2bf(p2.z), (short)f2bf(p2.w),
                          (short)f2bf(p3.x), (short)f2bf(p3.y), (short)f2bf(p3.z), (short)f2bf(p3.w)};
        }
        if (idx < 0) {
            a0 = (bf16x8)(short)0;
            a1 = (bf16x8)(short)0;
        }

        // B fragments: Wt[k][d][c], lane reads d = nt*16 + m, c = half*32 + quad*8 ..+8
        const unsigned short* wk = Wt + (size_t)k * 4096 + quad * 8;
#pragma unroll
        for (int nt = 0; nt < 4; ++nt) {
            const unsigned short* wn = wk + (nt * 16 + m) * 64;
            const bf16x8 b0 = *(const bf16x8*)(wn);
            const bf16x8 b1 = *(const bf16x8*)(wn + 32);
            f32x4& acc = nt == 0 ? acc0 : nt == 1 ? acc1 : nt == 2 ? acc2 : acc3;
            acc = __builtin_amdgcn_mfma_f32_16x16x32_bf16(a0, b0, acc, 0, 0, 0);
            acc = __builtin_amdgcn_mfma_f32_16x16x32_bf16(a1, b1, acc, 0, 0, 0);
        }
    }

    // C/D layout: col = lane&15, row = quad*4 + reg
#pragma unroll
    for (int nt = 0; nt < 4; ++nt) {
        const f32x4 acc = nt == 0 ? acc0 : nt == 1 ? acc1 : nt == 2 ? acc2 : acc3;
#pragma unroll
        for (int r = 0; r < 4; ++r) {
            out[(size_t)(v0 + quad * 4 + r) * CH + nt * 16 + m] = acc[r];
        }
    }
}

// ---- BN stats + apply ------------------------------------------------------

__launch_bounds__(256)
__global__ void reduce_stats(const float* __restrict__ out, float* __restrict__ stats) {
    const int tid = threadIdx.x;
    const int ch = tid & 63;
    float s = 0.f, s2 = 0.f;
    for (int e = blockIdx.x * 256 + tid; e < TOTAL; e += gridDim.x * 256) {
        const float x = out[e];
        s += x;
        s2 = fmaf(x, x, s2);
    }
    __shared__ float ls[256];
    __shared__ float ls2[256];
    ls[tid] = s;
    ls2[tid] = s2;
    __syncthreads();
    if (tid < 64) {
        s  = ls[tid] + ls[tid + 64] + ls[tid + 128] + ls[tid + 192];
        s2 = ls2[tid] + ls2[tid + 64] + ls2[tid + 128] + ls2[tid + 192];
        atomicAdd(&stats[ch], s);
        atomicAdd(&stats[64 + ch], s2);
    }
}

__global__ void finalize_stats(float* __restrict__ ws,
                               const float* __restrict__ gamma,
                               const float* __restrict__ beta) {
    const int c = threadIdx.x;   // 64 threads
    const float inv_n = 1.0f / (float)NVOX;
    const float mean = ws[c] * inv_n;
    const float var = ws[64 + c] * inv_n - mean * mean;
    const float scale = gamma[c] * rsqrtf(var + EPSV);
    ws[128 + c] = scale;
    ws[192 + c] = beta[c] - mean * scale;
}

__launch_bounds__(256)
__global__ void bn_relu(float* __restrict__ out, const float* __restrict__ ws) {
    const int e = blockIdx.x * 256 + threadIdx.x;   // float4 index
    float4* o4 = (float4*)out;
    const int cb = (e & 15) * 4;
    float4 x = o4[e];
    const float s0 = ws[128 + cb + 0], b0 = ws[192 + cb + 0];
    const float s1 = ws[128 + cb + 1], b1 = ws[192 + cb + 1];
    const float s2 = ws[128 + cb + 2], b2 = ws[192 + cb + 2];
    const float s3 = ws[128 + cb + 3], b3 = ws[192 + cb + 3];
    x.x = fmaxf(fmaf(x.x, s0, b0), 0.f);
    x.y = fmaxf(fmaf(x.y, s1, b1), 0.f);
    x.z = fmaxf(fmaf(x.z, s2, b2), 0.f);
    x.w = fmaxf(fmaf(x.w, s3, b3), 0.f);
    o4[e] = x;
}

extern "C" void kernel_launch(void* const* d_in, const int* in_sizes, int n_in,
                              void* d_out, int out_size, void* d_ws, size_t ws_size,
                              hipStream_t stream) {
    const float* feats  = (const float*)d_in[0];   // [N, 64]
    const float* weight = (const float*)d_in[1];   // [27, 64, 64]
    const float* gamma  = (const float*)d_in[2];   // [64]
    const float* beta   = (const float*)d_in[3];   // [64]
    const int*   nbr    = (const int*)d_in[4];     // [27, N]
    float* out = (float*)d_out;                    // [N, 64]
    float* ws  = (float*)d_ws;

    // ws layout (bytes):
    //   [0, 1024)                  : BN stats (sum, sumsq, scale, bias)
    //   [1024, 1024+221184)        : Wt bf16 [27][64][64]
    //   [222208, 222208+15360000)  : feats bf16 [N][64] (if ws_size allows)
    unsigned short* Wt     = (unsigned short*)((char*)d_ws + 1024);
    unsigned short* featsB = (unsigned short*)((char*)d_ws + 222208);
    const bool use_bf = ws_size >= (size_t)222208 + (size_t)NVOX * CH * 2;

    hipMemsetAsync(d_ws, 0, 256 * sizeof(float), stream);
    convert_w<<<(KVOL * CH * CH + 255) / 256, 256, 0, stream>>>(weight, Wt);
    if (use_bf) {
        convert_f<<<TOTAL / 4 / 256, 256, 0, stream>>>(feats, featsB);
        conv_mfma<true><<<NVOX / 64, 256, 0, stream>>>(featsB, feats, Wt, nbr, out);
    } else {
        conv_mfma<false><<<NVOX / 64, 256, 0, stream>>>(featsB, feats, Wt, nbr, out);
    }
    reduce_stats<<<512, 256, 0, stream>>>(out, ws);
    finalize_stats<<<1, 64, 0, stream>>>(ws, gamma, beta);
    bn_relu<<<TOTAL / 4 / 256, 256, 0, stream>>>(out, ws);
}

// Round 3
// 192.338 us; speedup vs baseline: 10.0135x; 1.7850x over previous
//
#include <hip/hip_runtime.h>

#define NVOX 120000
#define KVOL 27
#define CH 64
#define TOTAL (NVOX * CH)
#define EPSV 1e-5f
#define LDST 72   // LDS row stride in ushorts: 144 B = 9*16 B -> 16B-aligned, spreads all 32 banks

typedef __attribute__((ext_vector_type(8))) short bf16x8;
typedef __attribute__((ext_vector_type(4))) float f32x4;
typedef __attribute__((ext_vector_type(4))) unsigned int u32x4;

__device__ __forceinline__ unsigned short f2bf(float f) {
    unsigned int u = __builtin_bit_cast(unsigned int, f);
    u += 0x7FFFu + ((u >> 16) & 1u);          // RNE
    return (unsigned short)(u >> 16);
}

// ---- prep: weight transpose->bf16, feats->bf16, stats zero. One launch. ----
// blocks [0,432): wt (27*64*64 = 432*256); blocks [432, 432+7500): feats float4s
__global__ void prep(const float* __restrict__ w, unsigned short* __restrict__ wt,
                     const float* __restrict__ f, unsigned short* __restrict__ fb,
                     float* __restrict__ stats) {
    const int b = blockIdx.x;
    const int tid = threadIdx.x;
    if (b < 432) {
        const int t = b * 256 + tid;               // t = k*4096 + d*64 + c
        const int c = t & 63, d = (t >> 6) & 63, k = t >> 12;
        wt[t] = f2bf(w[k * 4096 + c * 64 + d]);
        if (b == 0 && tid < 128) stats[tid] = 0.f;
    } else {
        const int t = (b - 432) * 256 + tid;       // float4 index, 1,920,000 total
        const float4 x = ((const float4*)f)[t];
        ushort4 y;
        y.x = f2bf(x.x); y.y = f2bf(x.y); y.z = f2bf(x.z); y.w = f2bf(x.w);
        ((ushort4*)fb)[t] = y;
    }
}

// ---- gather one feature row as two bf16x8 fragments ------------------------
template <bool USE_BF>
__device__ __forceinline__ void gatherRow(const unsigned short* __restrict__ featsB,
                                          const float* __restrict__ feats32,
                                          int idx, int quad, bf16x8& a0, bf16x8& a1) {
    const int safe = idx < 0 ? 0 : idx;
    if (USE_BF) {
        const unsigned short* row = featsB + (size_t)safe * CH + quad * 8;
        a0 = *(const bf16x8*)row;
        a1 = *(const bf16x8*)(row + 32);
    } else {
        const float* row = feats32 + (size_t)safe * CH + quad * 8;
        const float4 p0 = *(const float4*)(row);
        const float4 p1 = *(const float4*)(row + 4);
        const float4 p2 = *(const float4*)(row + 32);
        const float4 p3 = *(const float4*)(row + 36);
        a0 = (bf16x8){(short)f2bf(p0.x), (short)f2bf(p0.y), (short)f2bf(p0.z), (short)f2bf(p0.w),
                      (short)f2bf(p1.x), (short)f2bf(p1.y), (short)f2bf(p1.z), (short)f2bf(p1.w)};
        a1 = (bf16x8){(short)f2bf(p2.x), (short)f2bf(p2.y), (short)f2bf(p2.z), (short)f2bf(p2.w),
                      (short)f2bf(p3.x), (short)f2bf(p3.y), (short)f2bf(p3.z), (short)f2bf(p3.w)};
    }
    if (idx < 0) {
        a0 = (bf16x8)(short)0;
        a1 = (bf16x8)(short)0;
    }
}

// ---- conv: gather-GEMM, 192 voxels/block, LDS-staged weights, fused stats --
template <bool USE_BF>
__launch_bounds__(256)
__global__ void conv_mfma(const unsigned short* __restrict__ featsB,
                          const float* __restrict__ feats32,
                          const unsigned short* __restrict__ Wt,
                          const int* __restrict__ nbr,
                          float* __restrict__ out,
                          float* __restrict__ stats) {
    __shared__ __align__(16) unsigned short ldsW[2][64 * LDST];
    const int tid = threadIdx.x;
    const int lane = tid & 63;
    const int wave = tid >> 6;
    const int m = lane & 15;
    const int quad = lane >> 4;
    const int v0 = blockIdx.x * 192 + wave * 48;   // 48 voxels per wave, 3 m-tiles

    // W staging: 512 chunks of 16B per k-slice; thread handles chunks tid, tid+256
    const int g0 = tid, g1 = tid + 256;
    const int l0 = (g0 >> 3) * LDST + (g0 & 7) * 8;   // ushort offset, 16B aligned
    const int l1 = (g1 >> 3) * LDST + (g1 & 7) * 8;

    unsigned short* bufR = &ldsW[0][0];
    unsigned short* bufW = &ldsW[1][0];

    // ---- prologue: stage W[0], prefetch W[1], nbr[0]->A[0], prefetch nbr[1]
    u32x4 wr0 = *(const u32x4*)(Wt + (size_t)g0 * 8);
    u32x4 wr1 = *(const u32x4*)(Wt + (size_t)g1 * 8);
    *(u32x4*)(bufR + l0) = wr0;
    *(u32x4*)(bufR + l1) = wr1;
    wr0 = *(const u32x4*)(Wt + 4096 + (size_t)g0 * 8);
    wr1 = *(const u32x4*)(Wt + 4096 + (size_t)g1 * 8);

    const int* nb0 = nbr + v0 + m;
    int ic0 = nb0[0], ic1 = nb0[16], ic2 = nb0[32];      // nbr[0]
    bf16x8 a[3][2];
    gatherRow<USE_BF>(featsB, feats32, ic0, quad, a[0][0], a[0][1]);
    gatherRow<USE_BF>(featsB, feats32, ic1, quad, a[1][0], a[1][1]);
    gatherRow<USE_BF>(featsB, feats32, ic2, quad, a[2][0], a[2][1]);
    const int* nb1 = nbr + NVOX + v0 + m;
    int ia0 = nb1[0], ia1 = nb1[16], ia2 = nb1[32];      // nbr[1]

    f32x4 acc[3][4];
#pragma unroll
    for (int t = 0; t < 3; ++t)
#pragma unroll
        for (int nt = 0; nt < 4; ++nt)
            acc[t][nt] = (f32x4){0.f, 0.f, 0.f, 0.f};

    __syncthreads();

    for (int k = 0; k < KVOL; ++k) {
        // stage W[k+1] (regs -> LDS write buffer)
        if (k < KVOL - 1) {
            *(u32x4*)(bufW + l0) = wr0;
            *(u32x4*)(bufW + l1) = wr1;
        }
        // prefetch W[k+2]
        if (k < KVOL - 2) {
            wr0 = *(const u32x4*)(Wt + (size_t)(k + 2) * 4096 + g0 * 8);
            wr1 = *(const u32x4*)(Wt + (size_t)(k + 2) * 4096 + g1 * 8);
        }
        // prefetch nbr[k+2]
        int ib0 = 0, ib1 = 0, ib2 = 0;
        if (k < KVOL - 2) {
            const int* nb = nbr + (size_t)(k + 2) * NVOX + v0 + m;
            ib0 = nb[0]; ib1 = nb[16]; ib2 = nb[32];
        }
        // prefetch A[k+1] (indices loaded last iteration)
        bf16x8 an[3][2];
        if (k < KVOL - 1) {
            gatherRow<USE_BF>(featsB, feats32, ia0, quad, an[0][0], an[0][1]);
            gatherRow<USE_BF>(featsB, feats32, ia1, quad, an[1][0], an[1][1]);
            gatherRow<USE_BF>(featsB, feats32, ia2, quad, an[2][0], an[2][1]);
        }

        // compute on a[] with B from bufR
        const unsigned short* wrow = bufR + m * LDST + quad * 8;
#pragma unroll
        for (int nt = 0; nt < 4; ++nt) {
            const bf16x8 b0 = *(const bf16x8*)(wrow + nt * 16 * LDST);
            const bf16x8 b1 = *(const bf16x8*)(wrow + nt * 16 * LDST + 32);
#pragma unroll
            for (int t = 0; t < 3; ++t) {
                acc[t][nt] = __builtin_amdgcn_mfma_f32_16x16x32_bf16(a[t][0], b0, acc[t][nt], 0, 0, 0);
                acc[t][nt] = __builtin_amdgcn_mfma_f32_16x16x32_bf16(a[t][1], b1, acc[t][nt], 0, 0, 0);
            }
        }

        if (k < KVOL - 1) {
#pragma unroll
            for (int t = 0; t < 3; ++t) {
                a[t][0] = an[t][0];
                a[t][1] = an[t][1];
            }
            ia0 = ib0; ia1 = ib1; ia2 = ib2;
            unsigned short* tmp = bufR; bufR = bufW; bufW = tmp;
            __syncthreads();
        }
    }

    // ---- epilogue: stores + fused BN statistics ----
    // D layout: col = lane&15 (=channel n mod 16), row = quad*4 + r (voxel within tile)
#pragma unroll
    for (int t = 0; t < 3; ++t) {
        float* ob = out + (size_t)(v0 + t * 16 + quad * 4) * CH + m;
#pragma unroll
        for (int nt = 0; nt < 4; ++nt)
#pragma unroll
            for (int r = 0; r < 4; ++r)
                ob[(size_t)r * CH + nt * 16] = acc[t][nt][r];
    }

#pragma unroll
    for (int nt = 0; nt < 4; ++nt) {
        float s = 0.f, s2 = 0.f;
#pragma unroll
        for (int t = 0; t < 3; ++t)
#pragma unroll
            for (int r = 0; r < 4; ++r) {
                const float x = acc[t][nt][r];
                s += x;
                s2 = fmaf(x, x, s2);
            }
        s  += __shfl_xor(s, 16);  s  += __shfl_xor(s, 32);
        s2 += __shfl_xor(s2, 16); s2 += __shfl_xor(s2, 32);
        if (lane < 16) {
            atomicAdd(&stats[nt * 16 + m], s);
            atomicAdd(&stats[64 + nt * 16 + m], s2);
        }
    }
}

// ---- bn_relu with inline finalize ------------------------------------------
__launch_bounds__(256)
__global__ void bn_relu(float* __restrict__ out, const float* __restrict__ stats,
                        const float* __restrict__ gamma, const float* __restrict__ beta) {
    __shared__ float sb[128];
    const int tid = threadIdx.x;
    if (tid < 64) {
        const float inv_n = 1.0f / (float)NVOX;
        const float mean = stats[tid] * inv_n;
        const float var = stats[64 + tid] * inv_n - mean * mean;
        const float sc = gamma[tid] * rsqrtf(var + EPSV);
        sb[tid] = sc;
        sb[64 + tid] = beta[tid] - mean * sc;
    }
    __syncthreads();
    const int e = blockIdx.x * 256 + tid;          // float4 index
    float4* o4 = (float4*)out;
    float4 x = o4[e];
    const int cb = (e & 15) * 4;
    x.x = fmaxf(fmaf(x.x, sb[cb + 0], sb[64 + cb + 0]), 0.f);
    x.y = fmaxf(fmaf(x.y, sb[cb + 1], sb[64 + cb + 1]), 0.f);
    x.z = fmaxf(fmaf(x.z, sb[cb + 2], sb[64 + cb + 2]), 0.f);
    x.w = fmaxf(fmaf(x.w, sb[cb + 3], sb[64 + cb + 3]), 0.f);
    o4[e] = x;
}

extern "C" void kernel_launch(void* const* d_in, const int* in_sizes, int n_in,
                              void* d_out, int out_size, void* d_ws, size_t ws_size,
                              hipStream_t stream) {
    const float* feats  = (const float*)d_in[0];   // [N, 64]
    const float* weight = (const float*)d_in[1];   // [27, 64, 64]
    const float* gamma  = (const float*)d_in[2];   // [64]
    const float* beta   = (const float*)d_in[3];   // [64]
    const int*   nbr    = (const int*)d_in[4];     // [27, N]
    float* out = (float*)d_out;                    // [N, 64]

    // ws layout: [0,512) stats; [512, 512+221184) Wt bf16; then featsB bf16
    float* stats = (float*)d_ws;
    unsigned short* Wt     = (unsigned short*)((char*)d_ws + 512);
    unsigned short* featsB = (unsigned short*)((char*)d_ws + 512 + 221184);
    const bool use_bf = ws_size >= (size_t)(512 + 221184) + (size_t)TOTAL * 2;

    if (use_bf) {
        prep<<<432 + TOTAL / 4 / 256, 256, 0, stream>>>(weight, Wt, feats, featsB, stats);
        conv_mfma<true><<<NVOX / 192, 256, 0, stream>>>(featsB, feats, Wt, nbr, out, stats);
    } else {
        prep<<<432, 256, 0, stream>>>(weight, Wt, feats, featsB, stats);
        conv_mfma<false><<<NVOX / 192, 256, 0, stream>>>(featsB, feats, Wt, nbr, out, stats);
    }
    bn_relu<<<TOTAL / 4 / 256, 256, 0, stream>>>(out, stats, gamma, beta);
}

// Round 4
// 175.388 us; speedup vs baseline: 10.9813x; 1.0966x over previous
//
#include <hip/hip_runtime.h>

#define NVOX 120000
#define KVOL 27
#define CH 64
#define TOTAL (NVOX * CH)
#define EPSV 1e-5f

typedef __attribute__((ext_vector_type(8))) short bf16x8;
typedef __attribute__((ext_vector_type(4))) float f32x4;
typedef __attribute__((ext_vector_type(4))) unsigned int u32x4;

__device__ __forceinline__ unsigned short f2bf(float f) {
    unsigned int u = __builtin_bit_cast(unsigned int, f);
    u += 0x7FFFu + ((u >> 16) & 1u);          // RNE
    return (unsigned short)(u >> 16);
}

// ---- prep ------------------------------------------------------------------
// blocks [0,432): weight fp32 [k][c][d] -> bf16 in MFMA-fragment order:
//   chunk(k, grp, lane) holds W[k][c = (grp&1)*32 + (lane>>4)*8 + j][d = (grp>>1)*16 + (lane&15)]
//   stored at wtf[((k*8 + grp)*64 + lane)*8 + j]  (16B chunks, lane-contiguous)
// blocks [432, 432+7500): feats fp32 -> bf16 (coalesced float4)
__global__ void prep(const float* __restrict__ w, unsigned short* __restrict__ wtf,
                     const float* __restrict__ f, unsigned short* __restrict__ fb,
                     float* __restrict__ stats) {
    const int b = blockIdx.x;
    const int tid = threadIdx.x;
    if (b < 432) {
        const int t = b * 256 + tid;               // t = k*4096 + c*64 + d (coalesced read)
        const int d = t & 63, c = (t >> 6) & 63, k = t >> 12;
        const int grp = (d >> 4) * 2 + (c >> 5);
        const int l = ((c & 31) >> 3) * 16 + (d & 15);
        const int j = c & 7;
        wtf[(((size_t)k * 8 + grp) * 64 + l) * 8 + j] = f2bf(w[t]);
        if (b == 0 && tid < 128) stats[tid] = 0.f;
    } else {
        const int t = (b - 432) * 256 + tid;       // float4 index, 1,920,000 total
        const float4 x = ((const float4*)f)[t];
        ushort4 y;
        y.x = f2bf(x.x); y.y = f2bf(x.y); y.z = f2bf(x.z); y.w = f2bf(x.w);
        ((ushort4*)fb)[t] = y;
    }
}

__device__ __forceinline__ void gatherRow(const unsigned short* __restrict__ fb,
                                          int idx, int q, bf16x8& a0, bf16x8& a1) {
    const int safe = idx < 0 ? 0 : idx;
    const unsigned short* row = fb + (size_t)safe * CH + q * 8;
    a0 = *(const bf16x8*)row;
    a1 = *(const bf16x8*)(row + 32);
    if (idx < 0) {
        a0 = (bf16x8)(short)0;
        a1 = (bf16x8)(short)0;
    }
}

// ---- conv: 64 voxels/block, 1875 blocks, frag-ordered LDS weights ----------
__launch_bounds__(256, 8)
__global__ void conv_mfma(const unsigned short* __restrict__ featsB,
                          const unsigned short* __restrict__ WtF,
                          const int* __restrict__ nbr,
                          float* __restrict__ out,
                          float* __restrict__ stats) {
    __shared__ __align__(16) unsigned short ldsW[2][4096];   // 2 x 8KB, frag order
    __shared__ float lstats[128];
    const int tid = threadIdx.x;
    const int lane = tid & 63;
    const int wave = tid >> 6;
    const int m = lane & 15;
    const int q = lane >> 4;
    const int v0 = blockIdx.x * 64 + wave * 16;

    const int c0 = tid, c1 = tid + 256;            // staging chunk ids (16B each)

    // prologue: stage W[0], prefetch W[1] into regs, start A pipeline
    u32x4 wr0 = *(const u32x4*)(WtF + (size_t)c0 * 8);
    u32x4 wr1 = *(const u32x4*)(WtF + (size_t)c1 * 8);
    *(u32x4*)(&ldsW[0][c0 * 8]) = wr0;
    *(u32x4*)(&ldsW[0][c1 * 8]) = wr1;
    wr0 = *(const u32x4*)(WtF + 4096 + (size_t)c0 * 8);
    wr1 = *(const u32x4*)(WtF + 4096 + (size_t)c1 * 8);

    int idx_cur = nbr[v0 + m];
    bf16x8 a0, a1;
    gatherRow(featsB, idx_cur, q, a0, a1);
    int idx_nxt = nbr[NVOX + v0 + m];

    f32x4 acc[4];
#pragma unroll
    for (int nt = 0; nt < 4; ++nt) acc[nt] = (f32x4){0.f, 0.f, 0.f, 0.f};
    if (tid < 128) lstats[tid] = 0.f;
    __syncthreads();

    int bsel = 0;
    for (int k = 0; k < KVOL; ++k) {
        const unsigned short* bufR = &ldsW[bsel][0];
        unsigned short* bufW = &ldsW[bsel ^ 1][0];

        if (k + 1 < KVOL) {                         // stage W[k+1]
            *(u32x4*)(bufW + c0 * 8) = wr0;
            *(u32x4*)(bufW + c1 * 8) = wr1;
        }
        if (k + 2 < KVOL) {                         // prefetch W[k+2]
            wr0 = *(const u32x4*)(WtF + (size_t)(k + 2) * 4096 + c0 * 8);
            wr1 = *(const u32x4*)(WtF + (size_t)(k + 2) * 4096 + c1 * 8);
        }
        int idx_n2 = 0;
        if (k + 2 < KVOL) idx_n2 = nbr[(size_t)(k + 2) * NVOX + v0 + m];
        bf16x8 an0, an1;
        if (k + 1 < KVOL) gatherRow(featsB, idx_nxt, q, an0, an1);

        // compute: B frags lane-contiguous in LDS (conflict-free b128)
#pragma unroll
        for (int nt = 0; nt < 4; ++nt) {
            const bf16x8 b0 = *(const bf16x8*)(bufR + (nt * 2 + 0) * 512 + lane * 8);
            const bf16x8 b1 = *(const bf16x8*)(bufR + (nt * 2 + 1) * 512 + lane * 8);
            acc[nt] = __builtin_amdgcn_mfma_f32_16x16x32_bf16(a0, b0, acc[nt], 0, 0, 0);
            acc[nt] = __builtin_amdgcn_mfma_f32_16x16x32_bf16(a1, b1, acc[nt], 0, 0, 0);
        }

        if (k + 1 < KVOL) {
            a0 = an0; a1 = an1;
            idx_nxt = idx_n2;
            bsel ^= 1;
            __syncthreads();
        }
    }

    // ---- epilogue: stores + block-reduced BN statistics ----
    // D layout: col = m (channel nt*16+m), row = q*4 + r (voxel)
    float* ob = out + (size_t)(v0 + q * 4) * CH + m;
#pragma unroll
    for (int nt = 0; nt < 4; ++nt)
#pragma unroll
        for (int r = 0; r < 4; ++r)
            ob[(size_t)r * CH + nt * 16] = acc[nt][r];

#pragma unroll
    for (int nt = 0; nt < 4; ++nt) {
        float s = 0.f, s2 = 0.f;
#pragma unroll
        for (int r = 0; r < 4; ++r) {
            const float x = acc[nt][r];
            s += x;
            s2 = fmaf(x, x, s2);
        }
        s  += __shfl_xor(s, 16);  s  += __shfl_xor(s, 32);
        s2 += __shfl_xor(s2, 16); s2 += __shfl_xor(s2, 32);
        if (lane < 16) {
            atomicAdd(&lstats[nt * 16 + m], s);
            atomicAdd(&lstats[64 + nt * 16 + m], s2);
        }
    }
    __syncthreads();
    if (tid < 128) atomicAdd(&stats[tid], lstats[tid]);
}

// ---- bn_relu with inline finalize ------------------------------------------
__launch_bounds__(256)
__global__ void bn_relu(float* __restrict__ out, const float* __restrict__ stats,
                        const float* __restrict__ gamma, const float* __restrict__ beta) {
    __shared__ float sb[128];
    const int tid = threadIdx.x;
    if (tid < 64) {
        const float inv_n = 1.0f / (float)NVOX;
        const float mean = stats[tid] * inv_n;
        const float var = stats[64 + tid] * inv_n - mean * mean;
        const float sc = gamma[tid] * rsqrtf(var + EPSV);
        sb[tid] = sc;
        sb[64 + tid] = beta[tid] - mean * sc;
    }
    __syncthreads();
    const int e = blockIdx.x * 256 + tid;          // float4 index
    float4* o4 = (float4*)out;
    float4 x = o4[e];
    const int cb = (e & 15) * 4;
    x.x = fmaxf(fmaf(x.x, sb[cb + 0], sb[64 + cb + 0]), 0.f);
    x.y = fmaxf(fmaf(x.y, sb[cb + 1], sb[64 + cb + 1]), 0.f);
    x.z = fmaxf(fmaf(x.z, sb[cb + 2], sb[64 + cb + 2]), 0.f);
    x.w = fmaxf(fmaf(x.w, sb[cb + 3], sb[64 + cb + 3]), 0.f);
    o4[e] = x;
}

extern "C" void kernel_launch(void* const* d_in, const int* in_sizes, int n_in,
                              void* d_out, int out_size, void* d_ws, size_t ws_size,
                              hipStream_t stream) {
    const float* feats  = (const float*)d_in[0];   // [N, 64]
    const float* weight = (const float*)d_in[1];   // [27, 64, 64]
    const float* gamma  = (const float*)d_in[2];   // [64]
    const float* beta   = (const float*)d_in[3];   // [64]
    const int*   nbr    = (const int*)d_in[4];     // [27, N]
    float* out = (float*)d_out;                    // [N, 64]

    // ws layout: [0,512) stats; [512, 512+221184) WtF bf16 frag-order; then featsB
    float* stats = (float*)d_ws;
    unsigned short* WtF    = (unsigned short*)((char*)d_ws + 512);
    unsigned short* featsB = (unsigned short*)((char*)d_ws + 512 + 221184);

    prep<<<432 + TOTAL / 4 / 256, 256, 0, stream>>>(weight, WtF, feats, featsB, stats);
    conv_mfma<<<NVOX / 64, 256, 0, stream>>>(featsB, WtF, nbr, out, stats);
    bn_relu<<<TOTAL / 4 / 256, 256, 0, stream>>>(out, stats, gamma, beta);
}